// Round 5
// baseline (249.097 us; speedup 1.0000x reference)
//
#include <hip/hip_runtime.h>

// PythonRenderer — 3-pass, L2-fit gather sets + 4 px/thread for MLP.
//   pass1: idx + vi + v2d  -> depth,bary   (set 3.4MB/XCD, batch-affine)
//   pass3: idx + vi + vn + bary -> vn_img  (set 3.4MB/XCD, batch-affine)
//   passB: idx + vti + vt + bary -> uv     (set 3.25MB, batch-independent)
// Each thread handles 4 consecutive pixels: 1 int4 idx load, 4 I3 gathers,
// 12 F3 gathers — all independent and issued together (R4 post-mortem: 20
// VGPRs meant serialized gathers; exposed L2/L3 latency was the limiter).
// Numerics: bit-exact vs numpy (epsclamp 1e-8 amplifies last-ulp ~1e16 on
// degenerate tris): fp contract off, exact left-to-right op order.
// Masked-bary reuse in passB/pass3 is exact (fm=1: b*fm==b bitwise; fm=0:
// uv collapses to base, vn to 0).

#define EPSV 1e-8f

__device__ __forceinline__ float epsclamp(float x) {
    return x < 0.0f ? fminf(x, -EPSV) : fmaxf(x, EPSV);
}

constexpr int Wd = 1024, Hd = 1024, Vd = 98304;
constexpr int NPIX = 1 << 22;          // B*H*W
constexpr int PPB  = 1 << 20;          // pixels per batch

struct I3 { int a, b, c; };            // 12B -> dwordx3
struct F3 { float x, y, z; };          // 12B -> dwordx3

// blockIdx (4096 blocks, 1024 px each) -> base pixel with XCD-batch affinity
// (assumes round-robin block->XCD; perf-only). Bijective.
__device__ __forceinline__ int base_pixel_swz(int j, int tid) {
    const int xcd = j & 7;
    const int b = xcd >> 1;
    const int sub = ((j >> 3) << 1) + (j & 1);   // [0,1024)
    return b * PPB + sub * 1024 + tid * 4;
}

// ---------------- pass1: depth + bary ----------------
__global__ __launch_bounds__(256) void pass1(
    const float* __restrict__ v2d,
    const int*   __restrict__ vi,
    const int*   __restrict__ index_img,
    float* __restrict__ out)
{
#pragma clang fp contract(off)
    const int pb = base_pixel_swz(blockIdx.x, threadIdx.x);
    const int b = pb >> 20;

    const int4 iv = *reinterpret_cast<const int4*>(index_img + pb);
    const int idx[4] = { iv.x, iv.y, iv.z, iv.w };

    I3 ii[4];
#pragma unroll
    for (int k = 0; k < 4; ++k) {
        const int f = idx[k] < 0 ? 0 : idx[k];
        ii[k] = *reinterpret_cast<const I3*>(vi + 3 * (size_t)f);
    }

    const float* __restrict__ vb = v2d + (size_t)b * Vd * 3;
    F3 P0[4], P1[4], P2[4];
#pragma unroll
    for (int k = 0; k < 4; ++k) {
        P0[k] = *reinterpret_cast<const F3*>(vb + 3 * (size_t)ii[k].a);
        P1[k] = *reinterpret_cast<const F3*>(vb + 3 * (size_t)ii[k].b);
        P2[k] = *reinterpret_cast<const F3*>(vb + 3 * (size_t)ii[k].c);
    }

    float dep[4], b0m[4], b1m[4], b2m[4];
#pragma unroll
    for (int k = 0; k < 4; ++k) {
        const int p = pb + k;
        const int x = p & (Wd - 1);
        const int y = (p >> 10) & (Hd - 1);
        const float fm = (idx[k] != -1) ? 1.0f : 0.0f;

        const float v01x = P1[k].x - P0[k].x, v01y = P1[k].y - P0[k].y;
        const float v02x = P2[k].x - P0[k].x, v02y = P2[k].y - P0[k].y;
        const float det = (v01x * v02y) - (v01y * v02x);
        const float denom = epsclamp(det);
        const float pxr = (float)x - P0[k].x;
        const float pyr = (float)y - P0[k].y;
        const float l1 = ((pxr * v02y) - (pyr * v02x)) / denom;
        const float l2 = ((pyr * v01x) - (pxr * v01y)) / denom;
        const float l0 = (1.0f - l1) - l2;

        const float w0 = 1.0f / epsclamp(P0[k].z);
        const float w1 = 1.0f / epsclamp(P1[k].z);
        const float w2 = 1.0f / epsclamp(P2[k].z);
        const float t0w = w0 * l0;
        const float t1w = w1 * l1;
        const float t2w = w2 * l2;
        const float zsum = (t0w + t1w) + t2w;
        const float zi = 1.0f / epsclamp(zsum);

        dep[k] = zi * fm;
        b0m[k] = (t0w * zi) * fm;
        b1m[k] = (t1w * zi) * fm;
        b2m[k] = (t2w * zi) * fm;
    }

    *reinterpret_cast<float4*>(out + pb) = make_float4(dep[0], dep[1], dep[2], dep[3]);
    float* __restrict__ ob = out + (size_t)NPIX + 3 * (size_t)pb;   // 16B aligned
    reinterpret_cast<float4*>(ob)[0] = make_float4(b0m[0], b1m[0], b2m[0], b0m[1]);
    reinterpret_cast<float4*>(ob)[1] = make_float4(b1m[1], b2m[1], b0m[2], b1m[2]);
    reinterpret_cast<float4*>(ob)[2] = make_float4(b2m[2], b0m[3], b1m[3], b2m[3]);
}

// ---------------- pass3: normals ----------------
__global__ __launch_bounds__(256) void pass3(
    const float* __restrict__ vn,
    const int*   __restrict__ vi,
    const int*   __restrict__ index_img,
    float* __restrict__ out)
{
#pragma clang fp contract(off)
    const int pb = base_pixel_swz(blockIdx.x, threadIdx.x);
    const int b = pb >> 20;

    const int4 iv = *reinterpret_cast<const int4*>(index_img + pb);
    const int idx[4] = { iv.x, iv.y, iv.z, iv.w };

    I3 ii[4];
#pragma unroll
    for (int k = 0; k < 4; ++k) {
        const int f = idx[k] < 0 ? 0 : idx[k];
        ii[k] = *reinterpret_cast<const I3*>(vi + 3 * (size_t)f);
    }

    const float* __restrict__ nb = vn + (size_t)b * Vd * 3;
    F3 N0[4], N1[4], N2[4];
#pragma unroll
    for (int k = 0; k < 4; ++k) {
        N0[k] = *reinterpret_cast<const F3*>(nb + 3 * (size_t)ii[k].a);
        N1[k] = *reinterpret_cast<const F3*>(nb + 3 * (size_t)ii[k].b);
        N2[k] = *reinterpret_cast<const F3*>(nb + 3 * (size_t)ii[k].c);
    }

    const float* __restrict__ bp = out + (size_t)NPIX + 3 * (size_t)pb;
    const float4 B0 = reinterpret_cast<const float4*>(bp)[0];
    const float4 B1 = reinterpret_cast<const float4*>(bp)[1];
    const float4 B2 = reinterpret_cast<const float4*>(bp)[2];
    const float b0m[4] = { B0.x, B0.w, B1.z, B2.y };
    const float b1m[4] = { B0.y, B1.x, B1.w, B2.z };
    const float b2m[4] = { B0.z, B1.y, B2.x, B2.w };

    float vnx[4], vny[4], vnz[4];
#pragma unroll
    for (int k = 0; k < 4; ++k) {
        const float fm = (idx[k] != -1) ? 1.0f : 0.0f;
        vnx[k] = (((N0[k].x * b0m[k]) + (N1[k].x * b1m[k])) + (N2[k].x * b2m[k])) * fm;
        vny[k] = (((N0[k].y * b0m[k]) + (N1[k].y * b1m[k])) + (N2[k].y * b2m[k])) * fm;
        vnz[k] = (((N0[k].z * b0m[k]) + (N1[k].z * b1m[k])) + (N2[k].z * b2m[k])) * fm;
    }

    float* __restrict__ on = out + (size_t)NPIX * 6 + 3 * (size_t)pb;  // 16B aligned
    reinterpret_cast<float4*>(on)[0] = make_float4(vnx[0], vny[0], vnz[0], vnx[1]);
    reinterpret_cast<float4*>(on)[1] = make_float4(vny[1], vnz[1], vnx[2], vny[2]);
    reinterpret_cast<float4*>(on)[2] = make_float4(vnz[2], vnx[3], vny[3], vnz[3]);
}

// ---------------- passB: uv ----------------
__global__ __launch_bounds__(256) void passB(
    const float* __restrict__ vt,
    const int*   __restrict__ vti,
    const int*   __restrict__ index_img,
    float* __restrict__ out)
{
#pragma clang fp contract(off)
    const int pb = blockIdx.x * 1024 + threadIdx.x * 4;

    const int4 iv = *reinterpret_cast<const int4*>(index_img + pb);
    const int idx[4] = { iv.x, iv.y, iv.z, iv.w };

    I3 tt[4];
#pragma unroll
    for (int k = 0; k < 4; ++k) {
        const int f = idx[k] < 0 ? 0 : idx[k];
        tt[k] = *reinterpret_cast<const I3*>(vti + 3 * (size_t)f);
    }

    const float2* __restrict__ vt2 = reinterpret_cast<const float2*>(vt);
    float2 tA[4], tB[4], tC[4];
#pragma unroll
    for (int k = 0; k < 4; ++k) {
        tA[k] = vt2[tt[k].a];
        tB[k] = vt2[tt[k].b];
        tC[k] = vt2[tt[k].c];
    }

    const float* __restrict__ bp = out + (size_t)NPIX + 3 * (size_t)pb;
    const float4 B0 = reinterpret_cast<const float4*>(bp)[0];
    const float4 B1 = reinterpret_cast<const float4*>(bp)[1];
    const float4 B2 = reinterpret_cast<const float4*>(bp)[2];
    const float b0[4] = { B0.x, B0.w, B1.z, B2.y };
    const float b1[4] = { B0.y, B1.x, B1.w, B2.z };
    const float b2[4] = { B0.z, B1.y, B2.x, B2.w };

    float u[4], v[4];
#pragma unroll
    for (int k = 0; k < 4; ++k) {
        const int p = pb + k;
        const int x = p & (Wd - 1);
        const int y = (p >> 10) & (Hd - 1);
        const float fm = (idx[k] != -1) ? 1.0f : 0.0f;

        float vtx = ((tA[k].x * b0[k]) + (tB[k].x * b1[k])) + (tC[k].x * b2[k]);
        float vty = ((tA[k].y * b0[k]) + (tB[k].y * b1[k])) + (tC[k].y * b2[k]);

        const float bx = (((float)x * 2.0f) + 1.0f) / (float)Wd - 1.0f;
        const float by = (((float)y * 2.0f) + 1.0f) / (float)Hd - 1.0f;
        u[k] = bx + (fm * (((vtx * 2.0f) - 1.0f) - bx));
        v[k] = by + (fm * (((vty * 2.0f) - 1.0f) - by));
    }

    float* __restrict__ ov = out + (size_t)NPIX * 4 + 2 * (size_t)pb;  // 16B aligned
    reinterpret_cast<float4*>(ov)[0] = make_float4(u[0], v[0], u[1], v[1]);
    reinterpret_cast<float4*>(ov)[1] = make_float4(u[2], v[2], u[3], v[3]);
}

extern "C" void kernel_launch(void* const* d_in, const int* in_sizes, int n_in,
                              void* d_out, int out_size, void* d_ws, size_t ws_size,
                              hipStream_t stream) {
    const float* v2d       = (const float*)d_in[0];
    const float* vt        = (const float*)d_in[1];
    const int*   vi        = (const int*)d_in[2];
    const int*   vti       = (const int*)d_in[3];
    const int*   index_img = (const int*)d_in[4];
    const float* vn        = (const float*)d_in[5];
    float* out = (float*)d_out;

    dim3 grid(NPIX / 1024), block(256);   // 4096 blocks, 4 px/thread
    pass1<<<grid, block, 0, stream>>>(v2d, vi, index_img, out);
    passB<<<grid, block, 0, stream>>>(vt, vti, index_img, out);
    pass3<<<grid, block, 0, stream>>>(vn, vi, index_img, out);
}